// Round 1
// baseline (2918.496 us; speedup 1.0000x reference)
//
#include <hip/hip_runtime.h>
#include <hip/hip_bf16.h>
#include <math.h>

// Problem constants
#define DD 128          // d_model
#define LL 25600        // H*W = 160*160
#define BB 2
#define WW 160
#define NTOT 51200      // B*L  (batch-norm N)

__device__ __forceinline__ float gelu_f(float v) {
    return 0.5f * v * (1.f + erff(v * 0.70710678118654752440f));
}

// ---------------------------------------------------------------------------
// Generic pointwise (1x1) conv:  out[o, n] = bias[o] + sum_c W[o*CIN+c] in[c, n]
// Tensors are [B, C, L] contiguous.  TWO_IN: input channels split over two
// 128-channel buffers.  TWO_OUT: output channels split over two 128-ch buffers.
// STATS: accumulate per-output-channel sum / sumsq (for training-mode BN).
// ---------------------------------------------------------------------------
template <int CIN, int O, bool TWO_IN, bool TWO_OUT, bool BIAS, bool STATS>
__global__ __launch_bounds__(256) void pw_kernel(
    const float* __restrict__ in1, const float* __restrict__ in2,
    const float* __restrict__ Wt, const float* __restrict__ bias,
    float* __restrict__ out1, float* __restrict__ out2,
    float* __restrict__ ssum, float* __restrict__ ssq)
{
    constexpr int NP = 64;
    __shared__ float Xs[CIN][NP];

    const int bx  = blockIdx.x;          // 0..799
    const int b   = bx / 400;
    const int p0  = (bx - b * 400) * NP;
    const int tid = threadIdx.x;

    for (int idx = tid; idx < CIN * NP; idx += 256) {
        const int c = idx >> 6, i = idx & 63;
        const float* src;
        if (TWO_IN) {
            src = (c < 128) ? (in1 + (size_t)(b * 128 + c) * LL)
                            : (in2 + (size_t)(b * 128 + (c - 128)) * LL);
        } else {
            src = in1 + (size_t)(b * CIN + c) * LL;
        }
        Xs[c][i] = src[p0 + i];
    }
    __syncthreads();

    const int i  = tid & 63;
    const int og = __builtin_amdgcn_readfirstlane(tid >> 6);  // wave-uniform
    constexpr int OPW = O / 4;  // outputs per wave

    for (int g = 0; g < OPW / 8; ++g) {
        const int ob = og * OPW + g * 8;
        float acc[8];
#pragma unroll
        for (int j = 0; j < 8; ++j) acc[j] = BIAS ? bias[ob + j] : 0.f;

#pragma unroll 4
        for (int c = 0; c < CIN; ++c) {
            const float xv = Xs[c][i];
#pragma unroll
            for (int j = 0; j < 8; ++j)
                acc[j] = fmaf(Wt[(ob + j) * CIN + c], xv, acc[j]);
        }

#pragma unroll
        for (int j = 0; j < 8; ++j) {
            const int o = ob + j;
            const float v = acc[j];
            float* dst;
            if (TWO_OUT) {
                dst = (o < 128) ? (out1 + (size_t)(b * 128 + o) * LL)
                                : (out2 + (size_t)(b * 128 + (o - 128)) * LL);
            } else {
                dst = out1 + (size_t)(b * O + o) * LL;
            }
            dst[p0 + i] = v;

            if (STATS) {
                float s1 = v, s2 = v * v;
#pragma unroll
                for (int m = 32; m >= 1; m >>= 1) {
                    s1 += __shfl_xor(s1, m, 64);
                    s2 += __shfl_xor(s2, m, 64);
                }
                if ((tid & 63) == 0) {
                    atomicAdd(&ssum[o], s1);
                    atomicAdd(&ssq[o], s2);
                }
            }
        }
    }
}

// ---------------------------------------------------------------------------
// Elementwise BN (from raw sums) + exact GELU, in place on a [B,128,L] unit.
// coff offsets into the stats arrays (for 256-channel stat sets).
// ---------------------------------------------------------------------------
__global__ __launch_bounds__(256) void bngelu_kernel(
    float* __restrict__ y, const float* __restrict__ ssum,
    const float* __restrict__ ssq, int coff)
{
    constexpr float invN = 1.f / (float)NTOT;
    const size_t idx = (size_t)blockIdx.x * 256 + threadIdx.x;  // float4 idx
    const int c = (int)((idx * 4) / LL) & 127;
    const float mean = ssum[c + coff] * invN;
    const float var  = ssq[c + coff] * invN - mean * mean;
    const float rs   = rsqrtf(var + 1e-5f);
    float4 v = reinterpret_cast<float4*>(y)[idx];
    v.x = gelu_f((v.x - mean) * rs);
    v.y = gelu_f((v.y - mean) * rs);
    v.z = gelu_f((v.z - mean) * rs);
    v.w = gelu_f((v.w - mean) * rs);
    reinterpret_cast<float4*>(y)[idx] = v;
}

// ---------------------------------------------------------------------------
// Depthwise 5x5, stride 1, SAME padding.  grid (10,10,B*128), block 256.
// ---------------------------------------------------------------------------
__global__ __launch_bounds__(256) void dw5_kernel(
    const float* __restrict__ in, const float* __restrict__ wdw,
    float* __restrict__ out)
{
    __shared__ float tile[20][20];
    const int bc = blockIdx.z;
    const int c  = bc & 127;
    const int h0 = blockIdx.y * 16, w0 = blockIdx.x * 16;
    const int tx = threadIdx.x & 15, ty = threadIdx.x >> 4;

    const float* src = in + (size_t)bc * LL;
    for (int idx = threadIdx.x; idx < 400; idx += 256) {
        const int r = idx / 20, col = idx - r * 20;
        const int gh = h0 + r - 2, gw = w0 + col - 2;
        float v = 0.f;
        if (gh >= 0 && gh < 160 && gw >= 0 && gw < 160) v = src[gh * WW + gw];
        tile[r][col] = v;
    }
    __syncthreads();

    const float* wp = wdw + c * 25;
    float wr[25];
#pragma unroll
    for (int t = 0; t < 25; ++t) wr[t] = wp[t];

    float acc = 0.f;
#pragma unroll
    for (int u = 0; u < 5; ++u)
#pragma unroll
        for (int v = 0; v < 5; ++v)
            acc = fmaf(wr[u * 5 + v], tile[ty + u][tx + v], acc);

    out[(size_t)bc * LL + (h0 + ty) * WW + (w0 + tx)] = acc;
}

// ---------------------------------------------------------------------------
// Attention reduce: kv[b,h,d,e] = (1/L2) sum_p relu(k[h*16+d,p]) * v[h*16+e,p]
//                   ksum[b,h,d] = (1/L2) sum_p relu(k[h*16+d,p])
// grid 256 = (b:2, h:16, chunk:8), block 256 = (d:16, e:16).
// ---------------------------------------------------------------------------
__global__ __launch_bounds__(256) void att_reduce_kernel(
    const float* __restrict__ K1, const float* __restrict__ K2,
    const float* __restrict__ V1, const float* __restrict__ V2,
    float* __restrict__ kv, float* __restrict__ ksum)
{
    constexpr int CHUNK = 3200;
    const int bx = blockIdx.x;
    const int b = bx >> 7;
    const int h = (bx >> 3) & 15;
    const int chunk = bx & 7;
    const int tid = threadIdx.x;
    const int d = tid >> 4, e = tid & 15;

    __shared__ float Ks[16][64];
    __shared__ float Vs[64][17];

    const int ch0 = h * 16;
    const float* kbase = (ch0 < 128) ? (K1 + (size_t)(b * 128 + ch0) * LL)
                                     : (K2 + (size_t)(b * 128 + ch0 - 128) * LL);
    const float* vbase = (ch0 < 128) ? (V1 + (size_t)(b * 128 + ch0) * LL)
                                     : (V2 + (size_t)(b * 128 + ch0 - 128) * LL);

    float kvacc = 0.f, ksacc = 0.f;
    const int tend = (chunk + 1) * CHUNK;
    for (int t0 = chunk * CHUNK; t0 < tend; t0 += 64) {
        __syncthreads();
        for (int idx = tid; idx < 1024; idx += 256) {
            const int cc = idx >> 6, ii = idx & 63;
            Ks[cc][ii] = fmaxf(kbase[(size_t)cc * LL + t0 + ii], 0.f);
            Vs[ii][cc] = vbase[(size_t)cc * LL + t0 + ii];
        }
        __syncthreads();
#pragma unroll 8
        for (int ii = 0; ii < 64; ++ii)
            kvacc = fmaf(Ks[d][ii], Vs[ii][e], kvacc);
        if (e == 0) {
#pragma unroll 8
            for (int ii = 0; ii < 64; ++ii) ksacc += Ks[d][ii];
        }
    }
    constexpr float s = 1.f / (float)LL;
    atomicAdd(&kv[(((size_t)b * 16 + h) * 16 + d) * 16 + e], kvacc * s);
    if (e == 0) atomicAdd(&ksum[((size_t)b * 16 + h) * 16 + d], ksacc * s);
}

// ---------------------------------------------------------------------------
// Attention apply: per position p, per head h:
//   s[d] = relu(q[h*16+d, p]);  z = 1/max(s . ksum[h], 1e-6)
//   out[h*16+e, p] = z * sum_d s[d] * kv[h,d,e]
// grid 200 blocks x 256 threads (thread = one position).
// ---------------------------------------------------------------------------
__global__ __launch_bounds__(256) void att_apply_kernel(
    const float* __restrict__ Q1, const float* __restrict__ Q2,
    const float* __restrict__ kv, const float* __restrict__ ksum,
    float* __restrict__ O1, float* __restrict__ O2)
{
    __shared__ float kvs[16][16][16];
    __shared__ float kss[16][16];

    const int pg = blockIdx.x * 256 + threadIdx.x;
    const int b  = pg / LL;          // blocks never straddle batches (LL%256==0)
    const int p  = pg - b * LL;
    const int tid = threadIdx.x;

    const float* kvb = kv + (size_t)b * 4096;
    for (int idx = tid; idx < 4096; idx += 256) ((float*)kvs)[idx] = kvb[idx];
    ((float*)kss)[tid] = ksum[b * 256 + tid];
    __syncthreads();

    for (int h = 0; h < 16; ++h) {
        const int ch0 = h * 16;
        const float* qb = (ch0 < 128) ? (Q1 + (size_t)(b * 128 + ch0) * LL)
                                      : (Q2 + (size_t)(b * 128 + ch0 - 128) * LL);
        float s[16];
#pragma unroll
        for (int d2 = 0; d2 < 16; ++d2) s[d2] = fmaxf(qb[(size_t)d2 * LL + p], 0.f);
        float denom = 0.f;
#pragma unroll
        for (int d2 = 0; d2 < 16; ++d2) denom = fmaf(s[d2], kss[h][d2], denom);
        const float z = 1.f / fmaxf(denom, 1e-6f);

        float* ob = (ch0 < 128) ? (O1 + (size_t)(b * 128 + ch0) * LL)
                                : (O2 + (size_t)(b * 128 + ch0 - 128) * LL);
#pragma unroll
        for (int e2 = 0; e2 < 16; ++e2) {
            float acc = 0.f;
#pragma unroll
            for (int d2 = 0; d2 < 16; ++d2)
                acc = fmaf(s[d2], kvs[h][d2][e2], acc);
            ob[(size_t)e2 * LL + p] = acc * z;
        }
    }
}

// ---------------------------------------------------------------------------
// Fused tail: t[c] = resid[c,p] + gelu(bn(yconv[c,p])) ; out = LN_c(t)*w+b
// grid 800 (64 positions per block), block 256.
// ---------------------------------------------------------------------------
__global__ __launch_bounds__(256) void fuse_ln_kernel(
    const float* __restrict__ yconv, const float* __restrict__ resid,
    const float* __restrict__ ssum, const float* __restrict__ ssq,
    const float* __restrict__ lnw, const float* __restrict__ lnb,
    float* __restrict__ outp)
{
    constexpr float invN = 1.f / (float)NTOT;
    __shared__ float t[128][64];
    __shared__ float mrs[128][2];
    __shared__ float red[4][64][2];
    __shared__ float mln[64], rln[64];

    const int bx = blockIdx.x;
    const int b = bx / 400, p0 = (bx - b * 400) * 64;
    const int tid = threadIdx.x;

    if (tid < 128) {
        const float mean = ssum[tid] * invN;
        const float var  = ssq[tid] * invN - mean * mean;
        mrs[tid][0] = mean;
        mrs[tid][1] = rsqrtf(var + 1e-5f);
    }
    __syncthreads();

    for (int idx = tid; idx < 8192; idx += 256) {
        const int c = idx >> 6, i = idx & 63;
        const size_t off = (size_t)(b * 128 + c) * LL + p0 + i;
        const float g = gelu_f((yconv[off] - mrs[c][0]) * mrs[c][1]);
        t[c][i] = g + resid[off];
    }
    __syncthreads();

    {
        const int i = tid & 63, q = tid >> 6;
        float ps = 0.f, pq = 0.f;
        for (int c = q * 32; c < q * 32 + 32; ++c) {
            const float v = t[c][i];
            ps += v; pq += v * v;
        }
        red[q][i][0] = ps; red[q][i][1] = pq;
    }
    __syncthreads();
    if (tid < 64) {
        float s1 = 0.f, s2 = 0.f;
#pragma unroll
        for (int q = 0; q < 4; ++q) { s1 += red[q][tid][0]; s2 += red[q][tid][1]; }
        const float m = s1 * (1.f / 128.f);
        const float var = s2 * (1.f / 128.f) - m * m;
        mln[tid] = m; rln[tid] = rsqrtf(var + 1e-5f);
    }
    __syncthreads();

    for (int idx = tid; idx < 8192; idx += 256) {
        const int c = idx >> 6, i = idx & 63;
        const float v = (t[c][i] - mln[i]) * rln[i] * lnw[c] + lnb[c];
        outp[(size_t)(b * 128 + c) * LL + p0 + i] = v;
    }
}

// ---------------------------------------------------------------------------
// wcomb[o, c2] = sum_m wmerge[o, m] * wproj[m, c2]    (128 x 256)
// ---------------------------------------------------------------------------
__global__ __launch_bounds__(256) void wcomb_kernel(
    const float* __restrict__ wmerge, const float* __restrict__ wproj,
    float* __restrict__ wc)
{
    const int o = blockIdx.x;
    const int c2 = threadIdx.x;
    float acc = 0.f;
#pragma unroll 4
    for (int m = 0; m < 128; ++m)
        acc = fmaf(wmerge[o * 128 + m], wproj[m * 256 + c2], acc);
    wc[o * 256 + c2] = acc;
}

// ---------------------------------------------------------------------------
extern "C" void kernel_launch(void* const* d_in, const int* in_sizes, int n_in,
                              void* d_out, int out_size, void* d_ws, size_t ws_size,
                              hipStream_t stream)
{
    const float* x      = (const float*)d_in[0];
    const float* source = (const float*)d_in[1];
    const float* wq = (const float*)d_in[2];  const float* bq = (const float*)d_in[3];
    const float* wk = (const float*)d_in[4];  const float* bk = (const float*)d_in[5];
    const float* wv = (const float*)d_in[6];  const float* bv = (const float*)d_in[7];
    const float* dwq = (const float*)d_in[8];  const float* pwq = (const float*)d_in[9];
    const float* dwk = (const float*)d_in[10]; const float* pwk = (const float*)d_in[11];
    const float* dwv = (const float*)d_in[12]; const float* pwv = (const float*)d_in[13];
    const float* wproj  = (const float*)d_in[14];
    const float* wmerge = (const float*)d_in[15]; const float* bmerge = (const float*)d_in[16];
    const float* wff1 = (const float*)d_in[17]; const float* bff1 = (const float*)d_in[18];
    const float* wff2 = (const float*)d_in[19]; const float* bff2 = (const float*)d_in[20];
    const float* ln1w = (const float*)d_in[21]; const float* ln1b = (const float*)d_in[22];
    const float* ln2w = (const float*)d_in[23]; const float* ln2b = (const float*)d_in[24];

    float* ws = (float*)d_ws;
    const size_t UNIT = (size_t)BB * 128 * LL;    // 6,553,600 floats
    float* U0 = ws + 0 * UNIT;   // Q   -> MSG (post-LN1)
    float* U1 = ws + 1 * UNIT;   // K   -> ATT half2
    float* U2 = ws + 2 * UNIT;   // V   -> Y2 (merge conv out)
    float* U3 = ws + 3 * UNIT;   // Q2  -> FF1 half1
    float* U4 = ws + 4 * UNIT;   // K2  -> FF1 half2
    float* U5 = ws + 5 * UNIT;   // V2  -> FF2
    float* U6 = ws + 6 * UNIT;   // dw temp -> ATT half1

    float* zbase = ws + 7 * UNIT;
    float* kv    = zbase;                 // 8192
    float* ksum  = zbase + 8192;          // 512
    float* sQ    = zbase + 8704;          // 128 sum + 128 sq
    float* sK    = sQ + 256;
    float* sV    = sK + 256;
    float* sM    = sV + 256;              // merge conv stats
    float* sF1   = sM + 256;              // 256 sum + 256 sq
    float* sF2   = sF1 + 512;             // 128 + 128
    const size_t zcount = 8192 + 512 + 256 * 4 + 512 + 256;
    float* wcomb = zbase + zcount;        // 128*256

    hipMemsetAsync(zbase, 0, zcount * sizeof(float), stream);
    wcomb_kernel<<<128, 256, 0, stream>>>(wmerge, wproj, wcomb);

    // q/k/v 1x1 convs with BN stats
    pw_kernel<128,128,false,false,true,true><<<800, 256, 0, stream>>>(
        x, nullptr, wq, bq, U0, nullptr, sQ, sQ + 128);
    pw_kernel<128,128,false,false,true,true><<<800, 256, 0, stream>>>(
        source, nullptr, wk, bk, U1, nullptr, sK, sK + 128);
    pw_kernel<128,128,false,false,true,true><<<800, 256, 0, stream>>>(
        source, nullptr, wv, bv, U2, nullptr, sV, sV + 128);

    // BN + GELU in place
    bngelu_kernel<<<6400, 256, 0, stream>>>(U0, sQ, sQ + 128, 0);
    bngelu_kernel<<<6400, 256, 0, stream>>>(U1, sK, sK + 128, 0);
    bngelu_kernel<<<6400, 256, 0, stream>>>(U2, sV, sV + 128, 0);

    // multiscale branch: depthwise 5x5 then pointwise
    dim3 dwgrid(10, 10, 256);
    dw5_kernel<<<dwgrid, 256, 0, stream>>>(U0, dwq, U6);
    pw_kernel<128,128,false,false,false,false><<<800, 256, 0, stream>>>(
        U6, nullptr, pwq, nullptr, U3, nullptr, nullptr, nullptr);
    dw5_kernel<<<dwgrid, 256, 0, stream>>>(U1, dwk, U6);
    pw_kernel<128,128,false,false,false,false><<<800, 256, 0, stream>>>(
        U6, nullptr, pwk, nullptr, U4, nullptr, nullptr, nullptr);
    dw5_kernel<<<dwgrid, 256, 0, stream>>>(U2, dwv, U6);
    pw_kernel<128,128,false,false,false,false><<<800, 256, 0, stream>>>(
        U6, nullptr, pwv, nullptr, U5, nullptr, nullptr, nullptr);

    // linear attention
    att_reduce_kernel<<<256, 256, 0, stream>>>(U1, U4, U2, U5, kv, ksum);
    att_apply_kernel<<<200, 256, 0, stream>>>(U0, U3, kv, ksum, U6, U1);

    // merged (wmerge @ wproj) conv with BN stats:  ATT(256ch) -> Y2(128ch)
    pw_kernel<256,128,true,false,true,true><<<800, 256, 0, stream>>>(
        U6, U1, wcomb, bmerge, U2, nullptr, sM, sM + 128);

    // msg = LN1(x + gelu(bn(Y2)))
    fuse_ln_kernel<<<800, 256, 0, stream>>>(U2, x, sM, sM + 128, ln1w, ln1b, U0);

    // FFN
    pw_kernel<128,256,false,true,true,true><<<800, 256, 0, stream>>>(
        U0, nullptr, wff1, bff1, U3, U4, sF1, sF1 + 256);
    bngelu_kernel<<<6400, 256, 0, stream>>>(U3, sF1, sF1 + 256, 0);
    bngelu_kernel<<<6400, 256, 0, stream>>>(U4, sF1, sF1 + 256, 128);
    pw_kernel<256,128,true,false,true,true><<<800, 256, 0, stream>>>(
        U3, U4, wff2, bff2, U5, nullptr, sF2, sF2 + 128);

    // out = LN2(msg + gelu(bn(FF2)))
    fuse_ln_kernel<<<800, 256, 0, stream>>>(U5, U0, sF2, sF2 + 128, ln2w, ln2b,
                                            (float*)d_out);
}

// Round 3
// 786.632 us; speedup vs baseline: 3.7101x; 3.7101x over previous
//
#include <hip/hip_runtime.h>
#include <math.h>

#define LL 25600          // H*W
#define NTOTF 51200.f     // B*L (batch-norm N)

using f16   = _Float16;
using f16x8 = __attribute__((ext_vector_type(8))) _Float16;
using f16x4 = __attribute__((ext_vector_type(4))) _Float16;
using f32x4 = __attribute__((ext_vector_type(4))) float;

__device__ __forceinline__ float gelu_f(float v) {
    return 0.5f * v * (1.f + erff(v * 0.70710678118654752440f));
}

// ---------------------------------------------------------------------------
// f16 MFMA GEMM:  Y[b, o, p] = bias[o] + sum_c W[o,c] * X[b, c, p]
//   X: [B, K, LL] (fp32 if IN32 else f16); W: fp32 [M,K] row-major
//   (TWOW: rows 0-127 from WA, 128-255 from WB); Y: f16 [B, M, LL].
//   LDG: apply BN(lstat)+GELU to X elements while staging to LDS.
//   STATS: accumulate per-o sum/sumsq of Y (pre-f16-rounding) into ostat[2M].
// Block: 256 thr (4 waves), wave owns M/4 rows.  Chunk: 64 positions.
// W in LDS (f16, XOR-swizzled); X chunk double-buffered in LDS.
// ---------------------------------------------------------------------------
template <int M, int K, bool IN32, bool LDG, bool TWOW, bool BIAS, bool STATS>
__global__ __launch_bounds__(256) void gemm_kernel(
    const void* __restrict__ Xin,
    const float* __restrict__ WA, const float* __restrict__ WB,
    const float* __restrict__ biasA, const float* __restrict__ biasB,
    const float* __restrict__ lstat,     // [2K] sum|sq for load-side BN
    f16* __restrict__ Y,
    float* __restrict__ ostat,           // [2M] sum|sq
    int nchunk)
{
    constexpr int MR  = M / 64;    // 16-row frags per wave
    constexpr int CPT = K / 4;     // channels staged per thread
    static_assert(CPT % 8 == 0, "");

    __shared__ f16 Ws[M * K];
    __shared__ f16 Xs[2][64 * K];
    __shared__ float lmrs[LDG ? 2 * K : 2];

    const int tid  = threadIdx.x;
    const int lane = tid & 63;
    const int wv   = tid >> 6;
    const int lm16 = lane & 15, lg = lane >> 4;
    const int row0 = wv * (M / 4);
    const int i    = lane;          // position within chunk
    const int g0   = wv * CPT;      // first channel staged by this thread

    // ---- weights -> LDS (fp32 -> f16, swizzled) ----
    for (int t = tid * 4; t < M * K; t += 1024) {
        const int row = t / K, col = t - row * K;        // col % 4 == 0
        const float* wp = (TWOW && row >= 128) ? (WB + (size_t)(row - 128) * K)
                                               : (WA + (size_t)row * K);
        const float4 w4 = *reinterpret_cast<const float4*>(wp + col);
        f16x4 v4; v4[0] = (f16)w4.x; v4[1] = (f16)w4.y;
        v4[2] = (f16)w4.z; v4[3] = (f16)w4.w;
        *reinterpret_cast<f16x4*>(&Ws[(size_t)row * K + (col ^ ((row & 7) << 3))]) = v4;
    }
    if (LDG) {
        for (int c = tid; c < K; c += 256) {
            const float m  = lstat[c] * (1.f / NTOTF);
            const float va = lstat[K + c] * (1.f / NTOTF) - m * m;
            lmrs[c] = m; lmrs[K + c] = rsqrtf(va + 1e-5f);
        }
    }

    // ---- bias (hoisted) + stats regs ----
    float bv[MR][4];
#pragma unroll
    for (int mr = 0; mr < MR; ++mr)
#pragma unroll
        for (int r = 0; r < 4; ++r) {
            if (BIAS) {
                const int o = row0 + mr * 16 + lg * 4 + r;
                bv[mr][r] = (TWOW && o >= 128) ? biasB[o - 128] : biasA[o];
            } else bv[mr][r] = 0.f;
        }
    float st1[MR][4], st2[MR][4];
#pragma unroll
    for (int mr = 0; mr < MR; ++mr)
#pragma unroll
        for (int r = 0; r < 4; ++r) { st1[mr][r] = 0.f; st2[mr][r] = 0.f; }

    float xr[CPT];
    auto load_regs = [&](int t) {
        const int bb = t / 400, pp0 = (t - bb * 400) * 64;
#pragma unroll
        for (int j = 0; j < CPT; ++j) {
            const size_t off = (size_t)(bb * K + g0 + j) * LL + pp0 + i;
            xr[j] = IN32 ? reinterpret_cast<const float*>(Xin)[off]
                         : (float)reinterpret_cast<const f16*>(Xin)[off];
        }
    };
    auto store_lds = [&](int buf) {
#pragma unroll
        for (int j = 0; j < CPT; j += 8) {
            f16x8 v8;
#pragma unroll
            for (int jj = 0; jj < 8; ++jj) {
                float v = xr[j + jj];
                if (LDG) {
                    const int c = g0 + j + jj;
                    v = gelu_f((v - lmrs[c]) * lmrs[K + c]);
                }
                v8[jj] = (f16)v;
            }
            const int c0 = g0 + j;
            *reinterpret_cast<f16x8*>(
                &Xs[buf][(size_t)i * K + (c0 ^ ((i & 7) << 3))]) = v8;
        }
    };

    __syncthreads();                       // Ws/lmrs visible
    int t = blockIdx.x;
    int cur = 0;
    load_regs(t);
    store_lds(0);
    __syncthreads();

    while (true) {
        const int tn = t + gridDim.x;
        const bool nxt = tn < nchunk;
        if (nxt) load_regs(tn);            // global loads in flight

        const int bb = t / 400, pp0 = (t - bb * 400) * 64;
        f32x4 acc[MR][4];
#pragma unroll
        for (int mr = 0; mr < MR; ++mr)
#pragma unroll
            for (int nr = 0; nr < 4; ++nr)
                acc[mr][nr] = (f32x4){0.f, 0.f, 0.f, 0.f};

#pragma unroll
        for (int k = 0; k < K / 32; ++k) {
            const int kc = k * 32 + lg * 8;
            f16x8 a[MR], bfr[4];
#pragma unroll
            for (int mr = 0; mr < MR; ++mr) {
                const int row = row0 + mr * 16 + lm16;
                a[mr] = *reinterpret_cast<const f16x8*>(
                    &Ws[(size_t)row * K + (kc ^ ((row & 7) << 3))]);
            }
#pragma unroll
            for (int nr = 0; nr < 4; ++nr) {
                const int pos = nr * 16 + lm16;
                bfr[nr] = *reinterpret_cast<const f16x8*>(
                    &Xs[cur][(size_t)pos * K + (kc ^ ((pos & 7) << 3))]);
            }
#pragma unroll
            for (int mr = 0; mr < MR; ++mr)
#pragma unroll
                for (int nr = 0; nr < 4; ++nr)
                    acc[mr][nr] = __builtin_amdgcn_mfma_f32_16x16x32_f16(
                        a[mr], bfr[nr], acc[mr][nr], 0, 0, 0);
        }

        // epilogue: bias, store f16, stats
#pragma unroll
        for (int mr = 0; mr < MR; ++mr)
#pragma unroll
            for (int r = 0; r < 4; ++r) {
                const int o = row0 + mr * 16 + lg * 4 + r;
                f16* yb = Y + (size_t)(bb * M + o) * LL + pp0 + lm16;
#pragma unroll
                for (int nr = 0; nr < 4; ++nr) {
                    const float v = acc[mr][nr][r] + bv[mr][r];
                    yb[nr * 16] = (f16)v;
                    if (STATS) { st1[mr][r] += v; st2[mr][r] += v * v; }
                }
            }

        if (!nxt) break;
        store_lds(cur ^ 1);
        __syncthreads();
        cur ^= 1; t = tn;
    }

    if (STATS) {
#pragma unroll
        for (int mr = 0; mr < MR; ++mr)
#pragma unroll
            for (int r = 0; r < 4; ++r) {
                float s1 = st1[mr][r], s2 = st2[mr][r];
#pragma unroll
                for (int m = 1; m < 16; m <<= 1) {
                    s1 += __shfl_xor(s1, m);
                    s2 += __shfl_xor(s2, m);
                }
                if (lm16 == 0) {
                    const int o = row0 + mr * 16 + lg * 4 + r;
                    atomicAdd(&ostat[o], s1);
                    atomicAdd(&ostat[M + o], s2);
                }
            }
    }
}

// ---------------------------------------------------------------------------
// Depthwise 5x5 SAME + fused input BN+GELU.  in: f16 [B,CH,LL] (use coff),
// stats: [2*SZ] sum|sq.  out: f16 [B,128,LL].  grid (10,10,256).
// ---------------------------------------------------------------------------
__global__ __launch_bounds__(256) void dw5_kernel(
    const f16* __restrict__ in, const float* __restrict__ stat,
    int CH, int coff, int SZ,
    const float* __restrict__ wdw, f16* __restrict__ outp)
{
    __shared__ float tile[20][20];
    const int bc = blockIdx.z;
    const int b = bc >> 7, c = bc & 127;
    const float mean = stat[coff + c] * (1.f / NTOTF);
    const float var  = stat[SZ + coff + c] * (1.f / NTOTF) - mean * mean;
    const float rs   = rsqrtf(var + 1e-5f);

    const int h0 = blockIdx.y * 16, w0 = blockIdx.x * 16;
    const int tx = threadIdx.x & 15, ty = threadIdx.x >> 4;

    const f16* src = in + (size_t)(b * CH + coff + c) * LL;
    for (int idx = threadIdx.x; idx < 400; idx += 256) {
        const int r = idx / 20, col = idx - r * 20;
        const int gh = h0 + r - 2, gw = w0 + col - 2;
        float v = 0.f;
        if (gh >= 0 && gh < 160 && gw >= 0 && gw < 160)
            v = gelu_f(((float)src[gh * 160 + gw] - mean) * rs);
        tile[r][col] = v;
    }
    __syncthreads();

    const float* wp = wdw + c * 25;
    float wr[25];
#pragma unroll
    for (int q = 0; q < 25; ++q) wr[q] = wp[q];

    float acc = 0.f;
#pragma unroll
    for (int u = 0; u < 5; ++u)
#pragma unroll
        for (int v = 0; v < 5; ++v)
            acc = fmaf(wr[u * 5 + v], tile[ty + u][tx + v], acc);

    outp[(size_t)(b * 128 + c) * LL + (h0 + ty) * 160 + (w0 + tx)] = (f16)acc;
}

// ---------------------------------------------------------------------------
// Attention reduce. heads 0-7 from KV (k rows 0-127 w/ BN+GELU+relu,
// v rows 128-255 w/ BN+GELU); heads 8-15 from K2 (relu) / V2 (raw).
// kvout[b,h,d,e] = (1/L) sum_p k*v ; ksum[b,h,d] = (1/L) sum_p k.
// grid 256 = (b:2, h:16, chunk:8), block 256 = (d:16, e:16).
// ---------------------------------------------------------------------------
__global__ __launch_bounds__(256) void att_reduce_kernel(
    const f16* __restrict__ KV, const f16* __restrict__ K2,
    const f16* __restrict__ V2, const float* __restrict__ stat,
    float* __restrict__ kvout, float* __restrict__ ksum)
{
    constexpr int CHUNK = 3200;
    const int bx = blockIdx.x;
    const int b = bx >> 7, h = (bx >> 3) & 15, chunk = bx & 7;
    const int tid = threadIdx.x;
    const int d = tid >> 4, e = tid & 15;
    const bool half1 = h < 8;

    __shared__ float Ks[16][64];
    __shared__ float Vs[64][17];
    __shared__ float mk[16], rk[16], mv[16], rv[16];

    if (tid < 16) {
        if (half1) {
            const int ck = h * 16 + tid;
            float m = stat[ck] * (1.f / NTOTF);
            float va = stat[256 + ck] * (1.f / NTOTF) - m * m;
            mk[tid] = m; rk[tid] = rsqrtf(va + 1e-5f);
            const int cv = 128 + h * 16 + tid;
            m = stat[cv] * (1.f / NTOTF);
            va = stat[256 + cv] * (1.f / NTOTF) - m * m;
            mv[tid] = m; rv[tid] = rsqrtf(va + 1e-5f);
        } else { mk[tid] = 0.f; rk[tid] = 1.f; mv[tid] = 0.f; rv[tid] = 1.f; }
    }

    const f16* kbase = half1 ? KV + (size_t)(b * 256 + h * 16) * LL
                             : K2 + (size_t)(b * 128 + (h - 8) * 16) * LL;
    const f16* vbase = half1 ? KV + (size_t)(b * 256 + 128 + h * 16) * LL
                             : V2 + (size_t)(b * 128 + (h - 8) * 16) * LL;

    float kvacc = 0.f, ksacc = 0.f;
    const int tend = (chunk + 1) * CHUNK;
    for (int t0 = chunk * CHUNK; t0 < tend; t0 += 64) {
        __syncthreads();
        for (int idx = tid; idx < 1024; idx += 256) {
            const int cc = idx >> 6, ii = idx & 63;
            float kl = (float)kbase[(size_t)cc * LL + t0 + ii];
            if (half1) kl = gelu_f((kl - mk[cc]) * rk[cc]);
            Ks[cc][ii] = fmaxf(kl, 0.f);
            float vl = (float)vbase[(size_t)cc * LL + t0 + ii];
            if (half1) vl = gelu_f((vl - mv[cc]) * rv[cc]);
            Vs[ii][cc] = vl;
        }
        __syncthreads();
#pragma unroll 8
        for (int ii = 0; ii < 64; ++ii)
            kvacc = fmaf(Ks[d][ii], Vs[ii][e], kvacc);
        if (e == 0) {
#pragma unroll 8
            for (int ii = 0; ii < 64; ++ii) ksacc += Ks[d][ii];
        }
    }
    constexpr float s = 1.f / (float)LL;
    atomicAdd(&kvout[(((size_t)b * 16 + h) * 16 + d) * 16 + e], kvacc * s);
    if (e == 0) atomicAdd(&ksum[((size_t)b * 16 + h) * 16 + d], ksacc * s);
}

// ---------------------------------------------------------------------------
// Attention apply. q heads 0-7: BN+GELU (statq) + relu; heads 8-15 (Q2): relu.
// att[b, h*16+e, p] f16.  grid 200 x 256 (thread = position).
// ---------------------------------------------------------------------------
__global__ __launch_bounds__(256) void att_apply_kernel(
    const f16* __restrict__ Q, const f16* __restrict__ Q2,
    const float* __restrict__ statq,
    const float* __restrict__ kvin, const float* __restrict__ ksum,
    f16* __restrict__ att)
{
    __shared__ float kvs[16][16][16];
    __shared__ float kss[16][16];
    __shared__ float mq[128], rq[128];

    const int pg = blockIdx.x * 256 + threadIdx.x;
    const int b = pg / LL, p = pg - b * LL;
    const int tid = threadIdx.x;

    const float* kvb = kvin + (size_t)b * 4096;
    for (int idx = tid; idx < 4096; idx += 256) ((float*)kvs)[idx] = kvb[idx];
    ((float*)kss)[tid] = ksum[b * 256 + tid];
    if (tid < 128) {
        const float m = statq[tid] * (1.f / NTOTF);
        const float va = statq[128 + tid] * (1.f / NTOTF) - m * m;
        mq[tid] = m; rq[tid] = rsqrtf(va + 1e-5f);
    }
    __syncthreads();

    for (int h = 0; h < 16; ++h) {
        const f16* qb = (h < 8) ? Q + (size_t)(b * 128 + h * 16) * LL
                                : Q2 + (size_t)(b * 128 + (h - 8) * 16) * LL;
        float s[16];
#pragma unroll
        for (int d2 = 0; d2 < 16; ++d2) {
            float v = (float)qb[(size_t)d2 * LL + p];
            if (h < 8) { const int ch = h * 16 + d2; v = gelu_f((v - mq[ch]) * rq[ch]); }
            s[d2] = fmaxf(v, 0.f);
        }
        float denom = 0.f;
#pragma unroll
        for (int d2 = 0; d2 < 16; ++d2) denom = fmaf(s[d2], kss[h][d2], denom);
        const float z = 1.f / fmaxf(denom, 1e-6f);

#pragma unroll
        for (int e2 = 0; e2 < 16; ++e2) {
            float acc = 0.f;
#pragma unroll
            for (int d2 = 0; d2 < 16; ++d2)
                acc = fmaf(s[d2], kvs[h][d2][e2], acc);
            att[(size_t)(b * 256 + h * 16 + e2) * LL + p] = (f16)(acc * z);
        }
    }
}

// ---------------------------------------------------------------------------
// Fused tail: t[c] = resid + gelu(bn(yconv)); out = LN_c(t)*w+b.
// grid 800 (64 positions/block), block 256.
// ---------------------------------------------------------------------------
template <bool RES32, bool OUT32>
__global__ __launch_bounds__(256) void fuse_ln_kernel(
    const f16* __restrict__ yconv, const void* __restrict__ residv,
    const float* __restrict__ stat,
    const float* __restrict__ lnw, const float* __restrict__ lnb,
    void* __restrict__ outv)
{
    __shared__ float t[128][64];
    __shared__ float mrs[128][2];
    __shared__ float red[4][64][2];
    __shared__ float mln[64], rln[64];

    const int bx = blockIdx.x;
    const int b = bx / 400, p0 = (bx - b * 400) * 64;
    const int tid = threadIdx.x;

    if (tid < 128) {
        const float mean = stat[tid] * (1.f / NTOTF);
        const float var  = stat[128 + tid] * (1.f / NTOTF) - mean * mean;
        mrs[tid][0] = mean; mrs[tid][1] = rsqrtf(var + 1e-5f);
    }
    __syncthreads();

    for (int idx = tid; idx < 8192; idx += 256) {
        const int c = idx >> 6, i = idx & 63;
        const size_t off = (size_t)(b * 128 + c) * LL + p0 + i;
        const float g = gelu_f(((float)yconv[off] - mrs[c][0]) * mrs[c][1]);
        const float r = RES32 ? reinterpret_cast<const float*>(residv)[off]
                              : (float)reinterpret_cast<const f16*>(residv)[off];
        t[c][i] = g + r;
    }
    __syncthreads();

    {
        const int i = tid & 63, q = tid >> 6;
        float ps = 0.f, pq = 0.f;
        for (int c = q * 32; c < q * 32 + 32; ++c) {
            const float v = t[c][i];
            ps += v; pq += v * v;
        }
        red[q][i][0] = ps; red[q][i][1] = pq;
    }
    __syncthreads();
    if (tid < 64) {
        float s1 = 0.f, s2 = 0.f;
#pragma unroll
        for (int q = 0; q < 4; ++q) { s1 += red[q][tid][0]; s2 += red[q][tid][1]; }
        const float m = s1 * (1.f / 128.f);
        const float var = s2 * (1.f / 128.f) - m * m;
        mln[tid] = m; rln[tid] = rsqrtf(var + 1e-5f);
    }
    __syncthreads();

    for (int idx = tid; idx < 8192; idx += 256) {
        const int c = idx >> 6, i = idx & 63;
        const float v = (t[c][i] - mln[i]) * rln[i] * lnw[c] + lnb[c];
        const size_t off = (size_t)(b * 128 + c) * LL + p0 + i;
        if (OUT32) reinterpret_cast<float*>(outv)[off] = v;
        else reinterpret_cast<f16*>(outv)[off] = (f16)v;
    }
}

// ---------------------------------------------------------------------------
// wcomb[o, c2] = sum_m wmerge[o, m] * wproj[m, c2]   (128 x 256, fp32)
// ---------------------------------------------------------------------------
__global__ __launch_bounds__(256) void wcomb_kernel(
    const float* __restrict__ wmerge, const float* __restrict__ wproj,
    float* __restrict__ wc)
{
    const int o = blockIdx.x;
    const int c2 = threadIdx.x;
    float acc = 0.f;
#pragma unroll 4
    for (int m = 0; m < 128; ++m)
        acc = fmaf(wmerge[o * 128 + m], wproj[m * 256 + c2], acc);
    wc[o * 256 + c2] = acc;
}

// ---------------------------------------------------------------------------
extern "C" void kernel_launch(void* const* d_in, const int* in_sizes, int n_in,
                              void* d_out, int out_size, void* d_ws, size_t ws_size,
                              hipStream_t stream)
{
    const float* x      = (const float*)d_in[0];
    const float* source = (const float*)d_in[1];
    const float* wq = (const float*)d_in[2];  const float* bq = (const float*)d_in[3];
    const float* wk = (const float*)d_in[4];  const float* bk = (const float*)d_in[5];
    const float* wvw = (const float*)d_in[6]; const float* bvb = (const float*)d_in[7];
    const float* dwq = (const float*)d_in[8];  const float* pwq = (const float*)d_in[9];
    const float* dwk = (const float*)d_in[10]; const float* pwk = (const float*)d_in[11];
    const float* dwv = (const float*)d_in[12]; const float* pwv = (const float*)d_in[13];
    const float* wproj  = (const float*)d_in[14];
    const float* wmerge = (const float*)d_in[15]; const float* bmerge = (const float*)d_in[16];
    const float* wff1 = (const float*)d_in[17]; const float* bff1 = (const float*)d_in[18];
    const float* wff2 = (const float*)d_in[19]; const float* bff2 = (const float*)d_in[20];
    const float* ln1w = (const float*)d_in[21]; const float* ln1b = (const float*)d_in[22];
    const float* ln2w = (const float*)d_in[23]; const float* ln2b = (const float*)d_in[24];

    const size_t UNITB = (size_t)2 * 128 * LL * sizeof(f16);  // 13,107,200 B
    char* w = (char*)d_ws;
    f16* qraw  = (f16*)w; w += UNITB;
    f16* kvraw = (f16*)w; w += 2 * UNITB;   // k: rows 0-127, v: 128-255
    f16* dwtmp = (f16*)w; w += UNITB;
    f16* q2raw = (f16*)w; w += UNITB;
    f16* k2raw = (f16*)w; w += UNITB;
    f16* v2raw = (f16*)w; w += UNITB;
    f16* att   = (f16*)w; w += 2 * UNITB;
    f16* y2raw = (f16*)w; w += UNITB;
    f16* msg   = (f16*)w; w += UNITB;
    f16* ff1raw= (f16*)w; w += 2 * UNITB;
    f16* ff2raw= (f16*)w; w += UNITB;

    float* zbase = (float*)w;
    float* kvred = zbase;              // 8192
    float* ksum  = zbase + 8192;       // 512
    float* sQ    = zbase + 8704;       // 256 (sum128|sq128)
    float* sKV   = sQ + 256;           // 512 (sum256|sq256)
    float* sM    = sKV + 512;          // 256
    float* sF1   = sM + 256;           // 512
    float* sF2   = sF1 + 512;          // 256
    const size_t zcount = 8192 + 512 + 256 + 512 + 256 + 512 + 256;  // 10496
    float* wcomb = zbase + zcount;     // 128*256 fp32

    hipMemsetAsync(zbase, 0, zcount * sizeof(float), stream);
    wcomb_kernel<<<128, 256, 0, stream>>>(wmerge, wproj, wcomb);

    // q / (k,v) 1x1 convs with BN stats
    gemm_kernel<128,128,true,false,false,true,true><<<512, 256, 0, stream>>>(
        x, wq, nullptr, bq, nullptr, nullptr, qraw, sQ, 800);
    gemm_kernel<256,128,true,false,true,true,true><<<256, 256, 0, stream>>>(
        source, wk, wvw, bk, bvb, nullptr, kvraw, sKV, 800);

    // multiscale branch: BN+GELU fused into dw5, then pointwise GEMM
    dim3 dwg(10, 10, 256);
    dw5_kernel<<<dwg, 256, 0, stream>>>(qraw, sQ, 128, 0, 128, dwq, dwtmp);
    gemm_kernel<128,128,false,false,false,false,false><<<512, 256, 0, stream>>>(
        dwtmp, pwq, nullptr, nullptr, nullptr, nullptr, q2raw, nullptr, 800);
    dw5_kernel<<<dwg, 256, 0, stream>>>(kvraw, sKV, 256, 0, 256, dwk, dwtmp);
    gemm_kernel<128,128,false,false,false,false,false><<<512, 256, 0, stream>>>(
        dwtmp, pwk, nullptr, nullptr, nullptr, nullptr, k2raw, nullptr, 800);
    dw5_kernel<<<dwg, 256, 0, stream>>>(kvraw, sKV, 256, 128, 256, dwv, dwtmp);
    gemm_kernel<128,128,false,false,false,false,false><<<512, 256, 0, stream>>>(
        dwtmp, pwv, nullptr, nullptr, nullptr, nullptr, v2raw, nullptr, 800);

    // linear attention
    att_reduce_kernel<<<256, 256, 0, stream>>>(kvraw, k2raw, v2raw, sKV, kvred, ksum);
    att_apply_kernel<<<200, 256, 0, stream>>>(qraw, q2raw, sQ, kvred, ksum, att);

    // merged (wmerge @ wproj) conv with BN stats
    gemm_kernel<128,256,false,false,false,true,true><<<256, 256, 0, stream>>>(
        att, wcomb, nullptr, bmerge, nullptr, nullptr, y2raw, sM, 800);

    // msg = LN1(x + gelu(bn(y2)))
    fuse_ln_kernel<true,false><<<800, 256, 0, stream>>>(
        y2raw, x, sM, ln1w, ln1b, msg);

    // FFN: ff1 GEMM; ff2 GEMM with BN+GELU fused on load
    gemm_kernel<256,128,false,false,false,true,true><<<256, 256, 0, stream>>>(
        msg, wff1, nullptr, bff1, nullptr, nullptr, ff1raw, sF1, 800);
    gemm_kernel<128,256,false,true,false,true,true><<<256, 256, 0, stream>>>(
        ff1raw, wff2, nullptr, bff2, nullptr, sF1, ff2raw, sF2, 800);

    // out = LN2(msg + gelu(bn(ff2)))
    fuse_ln_kernel<false,true><<<800, 256, 0, stream>>>(
        ff2raw, msg, sF2, ln2w, ln2b, (float*)d_out);
}

// Round 4
// 515.350 us; speedup vs baseline: 5.6631x; 1.5264x over previous
//
#include <hip/hip_runtime.h>
#include <math.h>

#define LL 25600          // H*W
#define NTOTF 51200.f     // B*L (batch-norm N)

using f16   = _Float16;
using f16x8 = __attribute__((ext_vector_type(8))) _Float16;
using f16x4 = __attribute__((ext_vector_type(4))) _Float16;
using f32x4 = __attribute__((ext_vector_type(4))) float;

__device__ __forceinline__ float gelu_f(float v) {
    return 0.5f * v * (1.f + erff(v * 0.70710678118654752440f));
}

// ---------------------------------------------------------------------------
// f16 MFMA GEMM:  Y[b, o, p] = bias[o] + sum_c W[o,c] * X[b, c, p]
//   X: [B, K, LL] (fp32 if IN32 else f16); W: fp32 [M,K] row-major
//   (TWOW: rows 0-127 from WA, 128-255 from WB); Y: f16 [B, M, LL].
//   LDG: apply BN(lstat)+GELU to X elements while staging to LDS.
//   STATS: accumulate per-o sum/sumsq of Y (pre-f16-rounding) into ostat[2M].
// Block: 256 thr (4 waves), wave owns M/4 rows.  Chunk: 64 positions.
// W in LDS (f16, XOR-swizzled); X chunk double-buffered in LDS.
// ---------------------------------------------------------------------------
template <int M, int K, bool IN32, bool LDG, bool TWOW, bool BIAS, bool STATS>
__global__ __launch_bounds__(256) void gemm_kernel(
    const void* __restrict__ Xin,
    const float* __restrict__ WA, const float* __restrict__ WB,
    const float* __restrict__ biasA, const float* __restrict__ biasB,
    const float* __restrict__ lstat,     // [2K] sum|sq for load-side BN
    f16* __restrict__ Y,
    float* __restrict__ ostat,           // [2M] sum|sq
    int nchunk)
{
    constexpr int MR  = M / 64;    // 16-row frags per wave
    constexpr int CPT = K / 4;     // channels staged per thread
    static_assert(CPT % 8 == 0, "");

    __shared__ f16 Ws[M * K];
    __shared__ f16 Xs[2][64 * K];
    __shared__ float lmrs[LDG ? 2 * K : 2];

    const int tid  = threadIdx.x;
    const int lane = tid & 63;
    const int wv   = tid >> 6;
    const int lm16 = lane & 15, lg = lane >> 4;
    const int row0 = wv * (M / 4);
    const int i    = lane;          // position within chunk
    const int g0   = wv * CPT;      // first channel staged by this thread

    // ---- weights -> LDS (fp32 -> f16, swizzled) ----
    for (int t = tid * 4; t < M * K; t += 1024) {
        const int row = t / K, col = t - row * K;        // col % 4 == 0
        const float* wp = (TWOW && row >= 128) ? (WB + (size_t)(row - 128) * K)
                                               : (WA + (size_t)row * K);
        const float4 w4 = *reinterpret_cast<const float4*>(wp + col);
        f16x4 v4; v4[0] = (f16)w4.x; v4[1] = (f16)w4.y;
        v4[2] = (f16)w4.z; v4[3] = (f16)w4.w;
        *reinterpret_cast<f16x4*>(&Ws[(size_t)row * K + (col ^ ((row & 7) << 3))]) = v4;
    }
    if (LDG) {
        for (int c = tid; c < K; c += 256) {
            const float m  = lstat[c] * (1.f / NTOTF);
            const float va = lstat[K + c] * (1.f / NTOTF) - m * m;
            lmrs[c] = m; lmrs[K + c] = rsqrtf(va + 1e-5f);
        }
    }

    // ---- bias (hoisted) + stats regs ----
    float bv[MR][4];
#pragma unroll
    for (int mr = 0; mr < MR; ++mr)
#pragma unroll
        for (int r = 0; r < 4; ++r) {
            if (BIAS) {
                const int o = row0 + mr * 16 + lg * 4 + r;
                bv[mr][r] = (TWOW && o >= 128) ? biasB[o - 128] : biasA[o];
            } else bv[mr][r] = 0.f;
        }
    float st1[MR][4], st2[MR][4];
#pragma unroll
    for (int mr = 0; mr < MR; ++mr)
#pragma unroll
        for (int r = 0; r < 4; ++r) { st1[mr][r] = 0.f; st2[mr][r] = 0.f; }

    float xr[CPT];
    auto load_regs = [&](int t) {
        const int bb = t / 400, pp0 = (t - bb * 400) * 64;
#pragma unroll
        for (int j = 0; j < CPT; ++j) {
            const size_t off = (size_t)(bb * K + g0 + j) * LL + pp0 + i;
            xr[j] = IN32 ? reinterpret_cast<const float*>(Xin)[off]
                         : (float)reinterpret_cast<const f16*>(Xin)[off];
        }
    };
    auto store_lds = [&](int buf) {
#pragma unroll
        for (int j = 0; j < CPT; j += 8) {
            f16x8 v8;
#pragma unroll
            for (int jj = 0; jj < 8; ++jj) {
                float v = xr[j + jj];
                if (LDG) {
                    const int c = g0 + j + jj;
                    v = gelu_f((v - lmrs[c]) * lmrs[K + c]);
                }
                v8[jj] = (f16)v;
            }
            const int c0 = g0 + j;
            *reinterpret_cast<f16x8*>(
                &Xs[buf][(size_t)i * K + (c0 ^ ((i & 7) << 3))]) = v8;
        }
    };

    __syncthreads();                       // Ws/lmrs visible
    int t = blockIdx.x;
    int cur = 0;
    load_regs(t);
    store_lds(0);
    __syncthreads();

    while (true) {
        const int tn = t + gridDim.x;
        const bool nxt = tn < nchunk;
        if (nxt) load_regs(tn);            // global loads in flight

        const int bb = t / 400, pp0 = (t - bb * 400) * 64;
        f32x4 acc[MR][4];
#pragma unroll
        for (int mr = 0; mr < MR; ++mr)
#pragma unroll
            for (int nr = 0; nr < 4; ++nr)
                acc[mr][nr] = (f32x4){0.f, 0.f, 0.f, 0.f};

#pragma unroll
        for (int k = 0; k < K / 32; ++k) {
            const int kc = k * 32 + lg * 8;
            f16x8 a[MR], bfr[4];
#pragma unroll
            for (int mr = 0; mr < MR; ++mr) {
                const int row = row0 + mr * 16 + lm16;
                a[mr] = *reinterpret_cast<const f16x8*>(
                    &Ws[(size_t)row * K + (kc ^ ((row & 7) << 3))]);
            }
#pragma unroll
            for (int nr = 0; nr < 4; ++nr) {
                const int pos = nr * 16 + lm16;
                bfr[nr] = *reinterpret_cast<const f16x8*>(
                    &Xs[cur][(size_t)pos * K + (kc ^ ((pos & 7) << 3))]);
            }
#pragma unroll
            for (int mr = 0; mr < MR; ++mr)
#pragma unroll
                for (int nr = 0; nr < 4; ++nr)
                    acc[mr][nr] = __builtin_amdgcn_mfma_f32_16x16x32_f16(
                        a[mr], bfr[nr], acc[mr][nr], 0, 0, 0);
        }

        // epilogue: bias, store f16, stats
#pragma unroll
        for (int mr = 0; mr < MR; ++mr)
#pragma unroll
            for (int r = 0; r < 4; ++r) {
                const int o = row0 + mr * 16 + lg * 4 + r;
                f16* yb = Y + (size_t)(bb * M + o) * LL + pp0 + lm16;
#pragma unroll
                for (int nr = 0; nr < 4; ++nr) {
                    const float v = acc[mr][nr][r] + bv[mr][r];
                    yb[nr * 16] = (f16)v;
                    if (STATS) { st1[mr][r] += v; st2[mr][r] += v * v; }
                }
            }

        if (!nxt) break;
        store_lds(cur ^ 1);
        __syncthreads();
        cur ^= 1; t = tn;
    }

    if (STATS) {
#pragma unroll
        for (int mr = 0; mr < MR; ++mr)
#pragma unroll
            for (int r = 0; r < 4; ++r) {
                float s1 = st1[mr][r], s2 = st2[mr][r];
#pragma unroll
                for (int m = 1; m < 16; m <<= 1) {
                    s1 += __shfl_xor(s1, m);
                    s2 += __shfl_xor(s2, m);
                }
                if (lm16 == 0) {
                    const int o = row0 + mr * 16 + lg * 4 + r;
                    atomicAdd(&ostat[o], s1);
                    atomicAdd(&ostat[M + o], s2);
                }
            }
    }
}

// ---------------------------------------------------------------------------
// Depthwise 5x5 SAME + fused input BN+GELU.  in: f16 [B,CH,LL] (use coff),
// stats: [2*SZ] sum|sq.  out: f16 [B,128,LL].  grid (10,10,256).
// ---------------------------------------------------------------------------
__global__ __launch_bounds__(256) void dw5_kernel(
    const f16* __restrict__ in, const float* __restrict__ stat,
    int CH, int coff, int SZ,
    const float* __restrict__ wdw, f16* __restrict__ outp)
{
    __shared__ float tile[20][20];
    const int bc = blockIdx.z;
    const int b = bc >> 7, c = bc & 127;
    const float mean = stat[coff + c] * (1.f / NTOTF);
    const float var  = stat[SZ + coff + c] * (1.f / NTOTF) - mean * mean;
    const float rs   = rsqrtf(var + 1e-5f);

    const int h0 = blockIdx.y * 16, w0 = blockIdx.x * 16;
    const int tx = threadIdx.x & 15, ty = threadIdx.x >> 4;

    const f16* src = in + (size_t)(b * CH + coff + c) * LL;
    for (int idx = threadIdx.x; idx < 400; idx += 256) {
        const int r = idx / 20, col = idx - r * 20;
        const int gh = h0 + r - 2, gw = w0 + col - 2;
        float v = 0.f;
        if (gh >= 0 && gh < 160 && gw >= 0 && gw < 160)
            v = gelu_f(((float)src[gh * 160 + gw] - mean) * rs);
        tile[r][col] = v;
    }
    __syncthreads();

    const float* wp = wdw + c * 25;
    float wr[25];
#pragma unroll
    for (int q = 0; q < 25; ++q) wr[q] = wp[q];

    float acc = 0.f;
#pragma unroll
    for (int u = 0; u < 5; ++u)
#pragma unroll
        for (int v = 0; v < 5; ++v)
            acc = fmaf(wr[u * 5 + v], tile[ty + u][tx + v], acc);

    outp[(size_t)(b * 128 + c) * LL + (h0 + ty) * 160 + (w0 + tx)] = (f16)acc;
}

// ---------------------------------------------------------------------------
// Attention reduce via MFMA outer product.  For each (b,h):
//   kv[d,e] = (1/L) sum_p krelu[d,p] * vact[e,p]   (16x16)
//   ksum[d] = (1/L) sum_p krelu[d,p]
// A-frag = krelu rows (d), B-frag = vact cols (e); both are contiguous 16B
// global loads per lane (lane&15 = channel, (lane>>4)*8 = pos offset).
// heads 0-7: k,v from KV with BN+GELU (k also relu); heads 8-15: K2 relu / V2.
// grid 800 = (b:2, h:16, chunk:25 of 1024 pos), block 256 (4 waves).
// ---------------------------------------------------------------------------
__global__ __launch_bounds__(256) void att_reduce_kernel(
    const f16* __restrict__ KV, const f16* __restrict__ K2,
    const f16* __restrict__ V2, const float* __restrict__ stat,
    float* __restrict__ kvout, float* __restrict__ ksum)
{
    __shared__ float kvred[4][256];

    const int bx = blockIdx.x;
    const int b = bx / 400;
    const int rem = bx - b * 400;
    const int h = rem / 25;
    const int chunk = rem - h * 25;
    const int tid = threadIdx.x;
    const int wv = tid >> 6, l = tid & 63;
    const int ch = l & 15, kg = l >> 4;
    const bool half1 = h < 8;

    // per-lane BN constants (channel = ch)
    float mk = 0.f, rk = 1.f, mv = 0.f, rv = 1.f;
    if (half1) {
        const int ck = h * 16 + ch;
        mk = stat[ck] * (1.f / NTOTF);
        float va = stat[256 + ck] * (1.f / NTOTF) - mk * mk;
        rk = rsqrtf(va + 1e-5f);
        const int cv = 128 + h * 16 + ch;
        mv = stat[cv] * (1.f / NTOTF);
        va = stat[256 + cv] * (1.f / NTOTF) - mv * mv;
        rv = rsqrtf(va + 1e-5f);
    }

    const f16* kbase = half1 ? KV + (size_t)(b * 256 + h * 16 + ch) * LL
                             : K2 + (size_t)(b * 128 + (h - 8) * 16 + ch) * LL;
    const f16* vbase = half1 ? KV + (size_t)(b * 256 + 128 + h * 16 + ch) * LL
                             : V2 + (size_t)(b * 128 + (h - 8) * 16 + ch) * LL;

    f32x4 acc = (f32x4){0.f, 0.f, 0.f, 0.f};
    float ksacc = 0.f;
    const int base = chunk * 1024 + wv * 256 + kg * 8;
#pragma unroll
    for (int it = 0; it < 8; ++it) {
        const int p = base + it * 32;
        const f16x8 kf = *reinterpret_cast<const f16x8*>(kbase + p);
        const f16x8 vf = *reinterpret_cast<const f16x8*>(vbase + p);
        f16x8 ka, vb;
#pragma unroll
        for (int j = 0; j < 8; ++j) {
            float kl = (float)kf[j];
            if (half1) kl = gelu_f((kl - mk) * rk);
            kl = fmaxf(kl, 0.f);
            ksacc += kl;
            ka[j] = (f16)kl;
            float vl = (float)vf[j];
            if (half1) vl = gelu_f((vl - mv) * rv);
            vb[j] = (f16)vl;
        }
        acc = __builtin_amdgcn_mfma_f32_16x16x32_f16(ka, vb, acc, 0, 0, 0);
    }

    // block-reduce the four per-wave 16x16 tiles, then one atomic set
    constexpr float s = 1.f / (float)LL;
#pragma unroll
    for (int r = 0; r < 4; ++r)
        kvred[wv][(kg * 4 + r) * 16 + ch] = acc[r];
    __syncthreads();
    {
        float t = kvred[0][tid] + kvred[1][tid] + kvred[2][tid] + kvred[3][tid];
        atomicAdd(&kvout[(size_t)(b * 16 + h) * 256 + tid], t * s);
    }

    // ksum: lanes {l, l^16, l^32, l^48} share a channel
    float s1 = ksacc;
    s1 += __shfl_xor(s1, 16);
    s1 += __shfl_xor(s1, 32);
    if (l < 16) atomicAdd(&ksum[(size_t)(b * 16 + h) * 16 + ch], s1 * s);
}

// ---------------------------------------------------------------------------
// Attention apply.  grid 3200 = (b:2, h:16, chunk:100 of 256 pos), block 256
// (thread = one position).  q heads 0-7: BN+GELU+relu; heads 8-15: relu.
// ---------------------------------------------------------------------------
__global__ __launch_bounds__(256) void att_apply_kernel(
    const f16* __restrict__ Q, const f16* __restrict__ Q2,
    const float* __restrict__ statq,
    const float* __restrict__ kvin, const float* __restrict__ ksumin,
    f16* __restrict__ att)
{
    __shared__ float kvs[256];
    __shared__ float kss[16];
    __shared__ float mq[16], rq[16];

    const int bx = blockIdx.x;
    const int b = bx / 1600;
    const int rem = bx - b * 1600;
    const int h = rem / 100;
    const int chunk = rem - h * 100;
    const int tid = threadIdx.x;
    const int p = chunk * 256 + tid;

    kvs[tid] = kvin[(size_t)b * 4096 + h * 256 + tid];
    if (tid < 16) {
        kss[tid] = ksumin[(size_t)b * 256 + h * 16 + tid];
        if (h < 8) {
            const int c2 = h * 16 + tid;
            const float m  = statq[c2] * (1.f / NTOTF);
            const float va = statq[128 + c2] * (1.f / NTOTF) - m * m;
            mq[tid] = m; rq[tid] = rsqrtf(va + 1e-5f);
        } else { mq[tid] = 0.f; rq[tid] = 1.f; }
    }
    __syncthreads();

    const f16* qb = (h < 8) ? Q + (size_t)(b * 128 + h * 16) * LL
                            : Q2 + (size_t)(b * 128 + (h - 8) * 16) * LL;
    float s[16];
#pragma unroll
    for (int d = 0; d < 16; ++d) {
        float v = (float)qb[(size_t)d * LL + p];
        if (h < 8) v = gelu_f((v - mq[d]) * rq[d]);
        s[d] = fmaxf(v, 0.f);
    }
    float denom = 0.f;
#pragma unroll
    for (int d = 0; d < 16; ++d) denom = fmaf(s[d], kss[d], denom);
    const float z = 1.f / fmaxf(denom, 1e-6f);

    f16* ob = att + (size_t)(b * 256 + h * 16) * LL + p;
#pragma unroll
    for (int e = 0; e < 16; ++e) {
        float acc = 0.f;
#pragma unroll
        for (int d = 0; d < 16; ++d)
            acc = fmaf(s[d], kvs[d * 16 + e], acc);
        ob[(size_t)e * LL] = (f16)(acc * z);
    }
}

// ---------------------------------------------------------------------------
// Fused tail: t[c] = resid + gelu(bn(yconv)); out = LN_c(t)*w+b.
// grid 800 (64 positions/block), block 256.
// ---------------------------------------------------------------------------
template <bool RES32, bool OUT32>
__global__ __launch_bounds__(256) void fuse_ln_kernel(
    const f16* __restrict__ yconv, const void* __restrict__ residv,
    const float* __restrict__ stat,
    const float* __restrict__ lnw, const float* __restrict__ lnb,
    void* __restrict__ outv)
{
    __shared__ float t[128][64];
    __shared__ float mrs[128][2];
    __shared__ float red[4][64][2];
    __shared__ float mln[64], rln[64];

    const int bx = blockIdx.x;
    const int b = bx / 400, p0 = (bx - b * 400) * 64;
    const int tid = threadIdx.x;

    if (tid < 128) {
        const float mean = stat[tid] * (1.f / NTOTF);
        const float var  = stat[128 + tid] * (1.f / NTOTF) - mean * mean;
        mrs[tid][0] = mean; mrs[tid][1] = rsqrtf(var + 1e-5f);
    }
    __syncthreads();

    for (int idx = tid; idx < 8192; idx += 256) {
        const int c = idx >> 6, i = idx & 63;
        const size_t off = (size_t)(b * 128 + c) * LL + p0 + i;
        const float g = gelu_f(((float)yconv[off] - mrs[c][0]) * mrs[c][1]);
        const float r = RES32 ? reinterpret_cast<const float*>(residv)[off]
                              : (float)reinterpret_cast<const f16*>(residv)[off];
        t[c][i] = g + r;
    }
    __syncthreads();

    {
        const int i = tid & 63, q = tid >> 6;
        float ps = 0.f, pq = 0.f;
        for (int c = q * 32; c < q * 32 + 32; ++c) {
            const float v = t[c][i];
            ps += v; pq += v * v;
        }
        red[q][i][0] = ps; red[q][i][1] = pq;
    }
    __syncthreads();
    if (tid < 64) {
        float s1 = 0.f, s2 = 0.f;
#pragma unroll
        for (int q = 0; q < 4; ++q) { s1 += red[q][tid][0]; s2 += red[q][tid][1]; }
        const float m = s1 * (1.f / 128.f);
        const float var = s2 * (1.f / 128.f) - m * m;
        mln[tid] = m; rln[tid] = rsqrtf(var + 1e-5f);
    }
    __syncthreads();

    for (int idx = tid; idx < 8192; idx += 256) {
        const int c = idx >> 6, i = idx & 63;
        const float v = (t[c][i] - mln[i]) * rln[i] * lnw[c] + lnb[c];
        const size_t off = (size_t)(b * 128 + c) * LL + p0 + i;
        if (OUT32) reinterpret_cast<float*>(outv)[off] = v;
        else reinterpret_cast<f16*>(outv)[off] = (f16)v;
    }
}

// ---------------------------------------------------------------------------
// wcomb[o, c2] = sum_m wmerge[o, m] * wproj[m, c2]   (128 x 256, fp32)
// ---------------------------------------------------------------------------
__global__ __launch_bounds__(256) void wcomb_kernel(
    const float* __restrict__ wmerge, const float* __restrict__ wproj,
    float* __restrict__ wc)
{
    const int o = blockIdx.x;
    const int c2 = threadIdx.x;
    float acc = 0.f;
#pragma unroll 4
    for (int m = 0; m < 128; ++m)
        acc = fmaf(wmerge[o * 128 + m], wproj[m * 256 + c2], acc);
    wc[o * 256 + c2] = acc;
}

// ---------------------------------------------------------------------------
extern "C" void kernel_launch(void* const* d_in, const int* in_sizes, int n_in,
                              void* d_out, int out_size, void* d_ws, size_t ws_size,
                              hipStream_t stream)
{
    const float* x      = (const float*)d_in[0];
    const float* source = (const float*)d_in[1];
    const float* wq = (const float*)d_in[2];  const float* bq = (const float*)d_in[3];
    const float* wk = (const float*)d_in[4];  const float* bk = (const float*)d_in[5];
    const float* wvw = (const float*)d_in[6]; const float* bvb = (const float*)d_in[7];
    const float* dwq = (const float*)d_in[8];  const float* pwq = (const float*)d_in[9];
    const float* dwk = (const float*)d_in[10]; const float* pwk = (const float*)d_in[11];
    const float* dwv = (const float*)d_in[12]; const float* pwv = (const float*)d_in[13];
    const float* wproj  = (const float*)d_in[14];
    const float* wmerge = (const float*)d_in[15]; const float* bmerge = (const float*)d_in[16];
    const float* wff1 = (const float*)d_in[17]; const float* bff1 = (const float*)d_in[18];
    const float* wff2 = (const float*)d_in[19]; const float* bff2 = (const float*)d_in[20];
    const float* ln1w = (const float*)d_in[21]; const float* ln1b = (const float*)d_in[22];
    const float* ln2w = (const float*)d_in[23]; const float* ln2b = (const float*)d_in[24];

    const size_t UNITB = (size_t)2 * 128 * LL * sizeof(f16);  // 13,107,200 B
    char* w = (char*)d_ws;
    f16* qraw  = (f16*)w; w += UNITB;
    f16* kvraw = (f16*)w; w += 2 * UNITB;   // k: rows 0-127, v: 128-255
    f16* dwtmp = (f16*)w; w += UNITB;
    f16* q2raw = (f16*)w; w += UNITB;
    f16* k2raw = (f16*)w; w += UNITB;
    f16* v2raw = (f16*)w; w += UNITB;
    f16* att   = (f16*)w; w += 2 * UNITB;
    f16* y2raw = (f16*)w; w += UNITB;
    f16* msg   = (f16*)w; w += UNITB;
    f16* ff1raw= (f16*)w; w += 2 * UNITB;
    f16* ff2raw= (f16*)w; w += UNITB;

    float* zbase = (float*)w;
    float* kvred = zbase;              // 8192
    float* ksum  = zbase + 8192;       // 512
    float* sQ    = zbase + 8704;       // 256 (sum128|sq128)
    float* sKV   = sQ + 256;           // 512 (sum256|sq256)
    float* sM    = sKV + 512;          // 256
    float* sF1   = sM + 256;           // 512
    float* sF2   = sF1 + 512;          // 256
    const size_t zcount = 8192 + 512 + 256 + 512 + 256 + 512 + 256;  // 10496
    float* wcomb = zbase + zcount;     // 128*256 fp32

    hipMemsetAsync(zbase, 0, zcount * sizeof(float), stream);
    wcomb_kernel<<<128, 256, 0, stream>>>(wmerge, wproj, wcomb);

    // q / (k,v) 1x1 convs with BN stats
    gemm_kernel<128,128,true,false,false,true,true><<<512, 256, 0, stream>>>(
        x, wq, nullptr, bq, nullptr, nullptr, qraw, sQ, 800);
    gemm_kernel<256,128,true,false,true,true,true><<<256, 256, 0, stream>>>(
        source, wk, wvw, bk, bvb, nullptr, kvraw, sKV, 800);

    // multiscale branch: BN+GELU fused into dw5, then pointwise GEMM
    dim3 dwg(10, 10, 256);
    dw5_kernel<<<dwg, 256, 0, stream>>>(qraw, sQ, 128, 0, 128, dwq, dwtmp);
    gemm_kernel<128,128,false,false,false,false,false><<<512, 256, 0, stream>>>(
        dwtmp, pwq, nullptr, nullptr, nullptr, nullptr, q2raw, nullptr, 800);
    dw5_kernel<<<dwg, 256, 0, stream>>>(kvraw, sKV, 256, 0, 256, dwk, dwtmp);
    gemm_kernel<128,128,false,false,false,false,false><<<512, 256, 0, stream>>>(
        dwtmp, pwk, nullptr, nullptr, nullptr, nullptr, k2raw, nullptr, 800);
    dw5_kernel<<<dwg, 256, 0, stream>>>(kvraw, sKV, 256, 128, 256, dwv, dwtmp);
    gemm_kernel<128,128,false,false,false,false,false><<<512, 256, 0, stream>>>(
        dwtmp, pwv, nullptr, nullptr, nullptr, nullptr, v2raw, nullptr, 800);

    // linear attention
    att_reduce_kernel<<<800, 256, 0, stream>>>(kvraw, k2raw, v2raw, sKV, kvred, ksum);
    att_apply_kernel<<<3200, 256, 0, stream>>>(qraw, q2raw, sQ, kvred, ksum, att);

    // merged (wmerge @ wproj) conv with BN stats
    gemm_kernel<128,256,false,false,false,true,true><<<256, 256, 0, stream>>>(
        att, wcomb, nullptr, bmerge, nullptr, nullptr, y2raw, sM, 800);

    // msg = LN1(x + gelu(bn(y2)))
    fuse_ln_kernel<true,false><<<800, 256, 0, stream>>>(
        y2raw, x, sM, ln1w, ln1b, msg);

    // FFN: ff1 GEMM; ff2 GEMM with BN+GELU fused on load
    gemm_kernel<256,128,false,false,false,true,true><<<256, 256, 0, stream>>>(
        msg, wff1, nullptr, bff1, nullptr, nullptr, ff1raw, sF1, 800);
    gemm_kernel<128,256,false,true,false,true,true><<<256, 256, 0, stream>>>(
        ff1raw, wff2, nullptr, bff2, nullptr, sF1, ff2raw, sF2, 800);

    // out = LN2(msg + gelu(bn(ff2)))
    fuse_ln_kernel<false,true><<<800, 256, 0, stream>>>(
        ff2raw, msg, sF2, ln2w, ln2b, (float*)d_out);
}